// Round 7
// baseline (543.579 us; speedup 1.0000x reference)
//
#include <hip/hip_runtime.h>
#include <hip/hip_bf16.h>
#include <stdint.h>

#define DD 32       // input dim
#define HH 64       // hidden dim
#define LOG2E 1.44269504088896340736f

typedef float f32x4 __attribute__((ext_vector_type(4)));
typedef short s16x8 __attribute__((ext_vector_type(8)));

// Single-instruction packed f32->bf16 (RNE). Low 16 bits = lo, high = hi.
__device__ __forceinline__ uint32_t cvtpk(float lo, float hi) {
  uint32_t r;
  asm("v_cvt_pk_bf16_f32 %0, %1, %2" : "=v"(r) : "v"(lo), "v"(hi));
  return r;
}

// Relaxed workgroup barrier: order LDS ops only; x-prefetch global loads stay
// in flight across timestep boundaries.
#define BAR() asm volatile("s_waitcnt lgkmcnt(0)\n\ts_barrier" ::: "memory")

// Block = 128 threads = 2 waves; 2 batch rows per block (A-rows dup x8).
// Wave w owns hidden cols [32w, 32w+32): 8 N-tiles (4 gates x 2 sub-tiles).
// D-layout with batch=row>>3 duplication: all 4 acc regs identical -> no select.
__global__ __launch_bounds__(128, 2)
void lstm_fused(const float* __restrict__ x,
                const float* __restrict__ W_ih,
                const float* __restrict__ W_hh,
                const float* __restrict__ b_ih,
                const float* __restrict__ b_hh,
                const float* __restrict__ fc_W,
                const float* __restrict__ fc_b,
                float* __restrict__ out,
                int T)
{
  const int tid  = threadIdx.x;
  const int w    = tid >> 6;     // wave 0..1 -> hidden-col half
  const int lane = tid & 63;
  const int lr   = lane & 15;    // A/D col index within tile
  const int lq   = lane >> 4;    // k-group 0..3
  const int arow = lr >> 3;      // batch row content of this A slot (dup x8)
  const int bm   = blockIdx.x * 2;

  __shared__ __align__(16) uint16_t hbuf[2][2 * HH]; // bf16 h, dbuf, linear

  // ---- persistent weights: 8 tiles/wave. tile tau: gate j=tau>>1, half hs=tau&1.
  // pre-scaled by log2e (2*log2e for g-gate).
  s16x8 Bx[8], Bh0[8], Bh1[8];
  #pragma unroll
  for (int tau = 0; tau < 8; ++tau) {
    const int j = tau >> 1;
    const int n = 64 * j + 32 * w + 16 * (tau & 1) + lr;  // gate-col
    const float sc = (j == 2) ? (2.0f * LOG2E) : LOG2E;
    {
      const float* p = W_ih + n * DD + lq * 8;
      f32x4 a = *(const f32x4*)p;
      f32x4 b = *(const f32x4*)(p + 4);
      union { uint32_t u[4]; s16x8 s; } pk;
      pk.u[0] = cvtpk(a[0]*sc, a[1]*sc); pk.u[1] = cvtpk(a[2]*sc, a[3]*sc);
      pk.u[2] = cvtpk(b[0]*sc, b[1]*sc); pk.u[3] = cvtpk(b[2]*sc, b[3]*sc);
      Bx[tau] = pk.s;
    }
    {
      const float* p = W_hh + n * HH + lq * 8;
      f32x4 a = *(const f32x4*)p;
      f32x4 b = *(const f32x4*)(p + 4);
      union { uint32_t u[4]; s16x8 s; } pk;
      pk.u[0] = cvtpk(a[0]*sc, a[1]*sc); pk.u[1] = cvtpk(a[2]*sc, a[3]*sc);
      pk.u[2] = cvtpk(b[0]*sc, b[1]*sc); pk.u[3] = cvtpk(b[2]*sc, b[3]*sc);
      Bh0[tau] = pk.s;
    }
    {
      const float* p = W_hh + n * HH + 32 + lq * 8;
      f32x4 a = *(const f32x4*)p;
      f32x4 b = *(const f32x4*)(p + 4);
      union { uint32_t u[4]; s16x8 s; } pk;
      pk.u[0] = cvtpk(a[0]*sc, a[1]*sc); pk.u[1] = cvtpk(a[2]*sc, a[3]*sc);
      pk.u[2] = cvtpk(b[0]*sc, b[1]*sc); pk.u[3] = cvtpk(b[2]*sc, b[3]*sc);
      Bh1[tau] = pk.s;
    }
  }

  // this lane's cell: batch b = lq>>1, hidden col hc = 32w + 16(lq&1) + lr
  float biasl[4];
  #pragma unroll
  for (int j = 0; j < 4; ++j) {
    const int n = 64 * j + 32 * w + 16 * (lq & 1) + lr;
    const float sc = (j == 2) ? (2.0f * LOG2E) : LOG2E;
    biasl[j] = (b_ih[n] + b_hh[n]) * sc;
  }

  hbuf[0][tid] = 0;  // 128 entries, 128 threads
  float c = 0.f;

  // hoisted LDS offsets
  const int roff0 = arow * HH + 8 * lq;        // h[arow][k=8lq..]
  const int roff1 = arow * HH + 32 + 8 * lq;   // h[arow][32+8lq..]
  const int woff  = (lq >> 1) * HH + 32 * w + 16 * (lq & 1) + lr;

  // 2-deep x prefetch with running pointer (addresses dup x8; coalescer dedups)
  const float* xbase = x + (size_t)(bm + arow) * (size_t)T * DD + lq * 8;
  f32x4 xa0 = *(const f32x4*)xbase;
  f32x4 xb0 = *(const f32x4*)(xbase + 4);
  f32x4 xa1 = *(const f32x4*)(xbase + DD);
  f32x4 xb1 = *(const f32x4*)(xbase + DD + 4);
  const float* xp = xbase + 2 * DD;

  __syncthreads();

  const f32x4 zz = {0.f, 0.f, 0.f, 0.f};

  auto step = [&](f32x4& xa, f32x4& xb, bool pf,
                  const uint16_t* __restrict__ hr, uint16_t* __restrict__ hw) {
    // pack current x into A fragment, then issue t+2 prefetch
    union { uint32_t u[4]; s16x8 s; } ax;
    ax.u[0] = cvtpk(xa[0], xa[1]); ax.u[1] = cvtpk(xa[2], xa[3]);
    ax.u[2] = cvtpk(xb[0], xb[1]); ax.u[3] = cvtpk(xb[2], xb[3]);
    if (pf) {
      xa = *(const f32x4*)xp;
      xb = *(const f32x4*)(xp + 4);
      xp += DD;
    }
    // x-part MFMAs (h-independent; overlap sibling wave / barrier skew)
    f32x4 acc[8];
    #pragma unroll
    for (int tau = 0; tau < 8; ++tau)
      acc[tau] = __builtin_amdgcn_mfma_f32_16x16x32_bf16(ax.s, Bx[tau], zz, 0, 0, 0);

    BAR();  // lgkmcnt-only: prev step's h writes visible, x loads in flight

    s16x8 ah0 = *(const s16x8*)(hr + roff0);
    s16x8 ah1 = *(const s16x8*)(hr + roff1);
    #pragma unroll
    for (int tau = 0; tau < 8; ++tau)
      acc[tau] = __builtin_amdgcn_mfma_f32_16x16x32_bf16(ah0, Bh0[tau], acc[tau], 0, 0, 0);
    #pragma unroll
    for (int tau = 0; tau < 8; ++tau)
      acc[tau] = __builtin_amdgcn_mfma_f32_16x16x32_bf16(ah1, Bh1[tau], acc[tau], 0, 0, 0);

    // gate j for this lane's cell lives in tile 2j+(lq&1), any reg (all equal);
    // one cndmask per gate, plus bias
    float g0 = ((lq & 1) ? acc[1][0] : acc[0][0]) + biasl[0];
    float g1 = ((lq & 1) ? acc[3][0] : acc[2][0]) + biasl[1];
    float g2 = ((lq & 1) ? acc[5][0] : acc[4][0]) + biasl[2];
    float g3 = ((lq & 1) ? acc[7][0] : acc[6][0]) + biasl[3];

    // single-cell LSTM update (weights pre-scaled by log2e)
    float ig = __builtin_amdgcn_rcpf(1.f + __builtin_amdgcn_exp2f(-g0));
    float fg = __builtin_amdgcn_rcpf(1.f + __builtin_amdgcn_exp2f(-g1));
    float gt = 1.f - 2.f * __builtin_amdgcn_rcpf(1.f + __builtin_amdgcn_exp2f(g2));
    float og = __builtin_amdgcn_rcpf(1.f + __builtin_amdgcn_exp2f(-g3));
    c = fg * c + ig * gt;
    float tc = 1.f - 2.f * __builtin_amdgcn_rcpf(
                 1.f + __builtin_amdgcn_exp2f((2.0f * LOG2E) * c));
    float hv = og * tc;
    hw[woff] = (uint16_t)cvtpk(hv, hv);  // one b16 write per lane
  };

  for (int t = 0; t < T - 2; t += 2) {
    step(xa0, xb0, true, hbuf[0], hbuf[1]);
    step(xa1, xb1, true, hbuf[1], hbuf[0]);
  }
  step(xa0, xb0, false, hbuf[0], hbuf[1]);
  step(xa1, xb1, false, hbuf[1], hbuf[0]);

  __syncthreads();  // final h (bf16) in hbuf[0], linear [b][hc]

  // ---- epilogue: logits = h_last @ fc_W^T + fc_b ----
  if (tid < 2 * 10) {
    const int m = tid / 10, cl = tid % 10;
    float s = fc_b[cl];
    const float* wr = fc_W + cl * HH;
    #pragma unroll
    for (int k = 0; k < HH; ++k) {
      union { uint32_t u; float f; } v;
      v.u = (uint32_t)hbuf[0][m * HH + k] << 16;
      s += v.f * wr[k];
    }
    out[(size_t)(bm + m) * 10 + cl] = s;
  }
}

extern "C" void kernel_launch(void* const* d_in, const int* in_sizes, int n_in,
                              void* d_out, int out_size, void* d_ws, size_t ws_size,
                              hipStream_t stream) {
  const float* x    = (const float*)d_in[0];
  const float* W_ih = (const float*)d_in[1];
  const float* W_hh = (const float*)d_in[2];
  const float* b_ih = (const float*)d_in[3];
  const float* b_hh = (const float*)d_in[4];
  const float* fc_W = (const float*)d_in[5];
  const float* fc_b = (const float*)d_in[6];
  float* out = (float*)d_out;

  const int B = out_size / 10;            // 2048
  const int T = in_sizes[0] / (B * DD);   // 1024

  dim3 grid(B / 2), block(128);
  hipLaunchKernelGGL(lstm_fused, grid, block, 0, stream,
                     x, W_ih, W_hh, b_ih, b_hh, fc_W, fc_b, out, T);
}

// Round 9
// 420.362 us; speedup vs baseline: 1.2931x; 1.2931x over previous
//
#include <hip/hip_runtime.h>
#include <hip/hip_bf16.h>
#include <stdint.h>

#define DD 32       // input dim
#define HH 64       // hidden dim
#define HSTRIDE 80  // LDS h-row stride in elems (160B)
#define LOG2E 1.44269504088896340736f

typedef float f32x4 __attribute__((ext_vector_type(4)));
typedef short s16x8 __attribute__((ext_vector_type(8)));

// Single-instruction packed f32->bf16 (RNE). Low 16 bits = lo, high = hi.
__device__ __forceinline__ uint32_t cvtpk(float lo, float hi) {
  uint32_t r;
  asm("v_cvt_pk_bf16_f32 %0, %1, %2" : "=v"(r) : "v"(lo), "v"(hi));
  return r;
}

// Relaxed workgroup barrier: order LDS ops only (x-prefetch global loads stay
// in flight). sched_barrier(0) pins the compiler: nothing crosses this point
// in either direction (rule #18 fence).
#define BAR() do {                                                    \
  asm volatile("s_waitcnt lgkmcnt(0)\n\ts_barrier" ::: "memory");     \
  __builtin_amdgcn_sched_barrier(0);                                  \
} while (0)

// 256 blocks x 4 waves. Each wave: 4 N-tiles (4 gates, cols 16w..16w+15) for
// TWO independent 4-row recurrence chains (8 batch rows/block, weights shared).
// A-row content batch=row>>2 (dup x4) => D rows 4lq+r all map to batch lq =>
// lane (lr,lq) owns cell (batch lq, col 16w+lr); gate j = acc[j][0]. No selects.
__global__ __launch_bounds__(256, 1)
void lstm_fused(const float* __restrict__ x,
                const float* __restrict__ W_ih,
                const float* __restrict__ W_hh,
                const float* __restrict__ b_ih,
                const float* __restrict__ b_hh,
                const float* __restrict__ fc_W,
                const float* __restrict__ fc_b,
                float* __restrict__ out,
                int T)
{
  const int tid  = threadIdx.x;
  const int w    = tid >> 6;     // wave 0..3 -> col group 16w
  const int lane = tid & 63;
  const int lr   = lane & 15;    // A/D col index within tile
  const int lq   = lane >> 4;    // k-group 0..3; ALSO this lane's batch row
  const int arow = lr >> 2;      // batch row content of A slot (dup x4)
  const int bm   = blockIdx.x * 8;

  // [buf][chain][row*HSTRIDE]
  __shared__ __align__(16) uint16_t hbuf[2][2][4 * HSTRIDE];

  // ---- persistent weights (shared by both chains): tile j = gate j.
  // pre-scaled by log2e (2*log2e for g-gate).
  s16x8 Bx[4], Bh0[4], Bh1[4];
  f32x4 biasv[4];
  #pragma unroll
  for (int j = 0; j < 4; ++j) {
    const int n = 64 * j + 16 * w + lr;
    const float sc = (j == 2) ? (2.0f * LOG2E) : LOG2E;
    {
      const float* p = W_ih + n * DD + lq * 8;
      f32x4 a = *(const f32x4*)p;
      f32x4 b = *(const f32x4*)(p + 4);
      union { uint32_t u[4]; s16x8 s; } pk;
      pk.u[0] = cvtpk(a[0]*sc, a[1]*sc); pk.u[1] = cvtpk(a[2]*sc, a[3]*sc);
      pk.u[2] = cvtpk(b[0]*sc, b[1]*sc); pk.u[3] = cvtpk(b[2]*sc, b[3]*sc);
      Bx[j] = pk.s;
    }
    {
      const float* p = W_hh + n * HH + lq * 8;
      f32x4 a = *(const f32x4*)p;
      f32x4 b = *(const f32x4*)(p + 4);
      union { uint32_t u[4]; s16x8 s; } pk;
      pk.u[0] = cvtpk(a[0]*sc, a[1]*sc); pk.u[1] = cvtpk(a[2]*sc, a[3]*sc);
      pk.u[2] = cvtpk(b[0]*sc, b[1]*sc); pk.u[3] = cvtpk(b[2]*sc, b[3]*sc);
      Bh0[j] = pk.s;
    }
    {
      const float* p = W_hh + n * HH + 32 + lq * 8;
      f32x4 a = *(const f32x4*)p;
      f32x4 b = *(const f32x4*)(p + 4);
      union { uint32_t u[4]; s16x8 s; } pk;
      pk.u[0] = cvtpk(a[0]*sc, a[1]*sc); pk.u[1] = cvtpk(a[2]*sc, a[3]*sc);
      pk.u[2] = cvtpk(b[0]*sc, b[1]*sc); pk.u[3] = cvtpk(b[2]*sc, b[3]*sc);
      Bh1[j] = pk.s;
    }
    const float bb = (b_ih[n] + b_hh[n]) * sc;
    biasv[j] = (f32x4){bb, bb, bb, bb};
  }

  for (int i = tid; i < 2 * 2 * 4 * HSTRIDE; i += 256) ((uint16_t*)hbuf)[i] = 0;

  float cA = 0.f, cB = 0.f;   // one cell per chain: (batch lq, col 16w+lr)

  // hoisted LDS offsets (linear layout, consistent on read & write)
  const int roff0 = arow * HSTRIDE + 8 * lq;   // h[arow][8lq..]
  const int roff1 = roff0 + 32;                // h[arow][32+8lq..]
  const int woff  = lq * HSTRIDE + 16 * w + lr;

  // 2-deep x prefetch per chain, running pointers (dup x4; coalescer dedups)
  const float* xbA = x + (size_t)(bm +     arow) * (size_t)T * DD + lq * 8;
  const float* xbB = x + (size_t)(bm + 4 + arow) * (size_t)T * DD + lq * 8;
  f32x4 xa0A = *(const f32x4*)xbA;        f32x4 xb0A = *(const f32x4*)(xbA + 4);
  f32x4 xa1A = *(const f32x4*)(xbA + DD); f32x4 xb1A = *(const f32x4*)(xbA + DD + 4);
  f32x4 xa0B = *(const f32x4*)xbB;        f32x4 xb0B = *(const f32x4*)(xbB + 4);
  f32x4 xa1B = *(const f32x4*)(xbB + DD); f32x4 xb1B = *(const f32x4*)(xbB + DD + 4);
  const float* xpA = xbA + 2 * DD;
  const float* xpB = xbB + 2 * DD;

  __syncthreads();

  auto step = [&](f32x4& xaA, f32x4& xbAv, f32x4& xaB, f32x4& xbBv, bool pf,
                  const uint16_t* hrA, const uint16_t* hrB,
                  uint16_t* hwA, uint16_t* hwB) {
    BAR();  // prev step's h writes visible; global x loads stay in flight

    // h reads, both chains (latency shadowed by the packs below)
    s16x8 a0A = *(const s16x8*)(hrA + roff0);
    s16x8 a1A = *(const s16x8*)(hrA + roff1);
    s16x8 a0B = *(const s16x8*)(hrB + roff0);
    s16x8 a1B = *(const s16x8*)(hrB + roff1);

    // pack both chains' x into A fragments, then issue t+2 prefetches
    union { uint32_t u[4]; s16x8 s; } axA, axB;
    axA.u[0] = cvtpk(xaA[0], xaA[1]);   axA.u[1] = cvtpk(xaA[2], xaA[3]);
    axA.u[2] = cvtpk(xbAv[0], xbAv[1]); axA.u[3] = cvtpk(xbAv[2], xbAv[3]);
    axB.u[0] = cvtpk(xaB[0], xaB[1]);   axB.u[1] = cvtpk(xaB[2], xaB[3]);
    axB.u[2] = cvtpk(xbBv[0], xbBv[1]); axB.u[3] = cvtpk(xbBv[2], xbBv[3]);
    if (pf) {
      xaA = *(const f32x4*)xpA; xbAv = *(const f32x4*)(xpA + 4); xpA += DD;
      xaB = *(const f32x4*)xpB; xbBv = *(const f32x4*)(xpB + 4); xpB += DD;
    }

    // MFMAs: x-part then h-parts, two independent chains pipeline
    f32x4 accA[4], accB[4];
    #pragma unroll
    for (int j = 0; j < 4; ++j)
      accA[j] = __builtin_amdgcn_mfma_f32_16x16x32_bf16(axA.s, Bx[j], biasv[j], 0, 0, 0);
    #pragma unroll
    for (int j = 0; j < 4; ++j)
      accB[j] = __builtin_amdgcn_mfma_f32_16x16x32_bf16(axB.s, Bx[j], biasv[j], 0, 0, 0);
    #pragma unroll
    for (int j = 0; j < 4; ++j)
      accA[j] = __builtin_amdgcn_mfma_f32_16x16x32_bf16(a0A, Bh0[j], accA[j], 0, 0, 0);
    #pragma unroll
    for (int j = 0; j < 4; ++j)
      accB[j] = __builtin_amdgcn_mfma_f32_16x16x32_bf16(a0B, Bh0[j], accB[j], 0, 0, 0);
    #pragma unroll
    for (int j = 0; j < 4; ++j)
      accA[j] = __builtin_amdgcn_mfma_f32_16x16x32_bf16(a1A, Bh1[j], accA[j], 0, 0, 0);
    #pragma unroll
    for (int j = 0; j < 4; ++j)
      accB[j] = __builtin_amdgcn_mfma_f32_16x16x32_bf16(a1B, Bh1[j], accB[j], 0, 0, 0);

    // cell updates, two independent chains (trans chains interleave)
    float g0A = accA[0][0], g1A = accA[1][0], g2A = accA[2][0], g3A = accA[3][0];
    float g0B = accB[0][0], g1B = accB[1][0], g2B = accB[2][0], g3B = accB[3][0];

    float igA = __builtin_amdgcn_rcpf(1.f + __builtin_amdgcn_exp2f(-g0A));
    float igB = __builtin_amdgcn_rcpf(1.f + __builtin_amdgcn_exp2f(-g0B));
    float fgA = __builtin_amdgcn_rcpf(1.f + __builtin_amdgcn_exp2f(-g1A));
    float fgB = __builtin_amdgcn_rcpf(1.f + __builtin_amdgcn_exp2f(-g1B));
    float gtA = 1.f - 2.f * __builtin_amdgcn_rcpf(1.f + __builtin_amdgcn_exp2f(g2A));
    float gtB = 1.f - 2.f * __builtin_amdgcn_rcpf(1.f + __builtin_amdgcn_exp2f(g2B));
    float ogA = __builtin_amdgcn_rcpf(1.f + __builtin_amdgcn_exp2f(-g3A));
    float ogB = __builtin_amdgcn_rcpf(1.f + __builtin_amdgcn_exp2f(-g3B));
    cA = fgA * cA + igA * gtA;
    cB = fgB * cB + igB * gtB;
    float tcA = 1.f - 2.f * __builtin_amdgcn_rcpf(
                  1.f + __builtin_amdgcn_exp2f((2.0f * LOG2E) * cA));
    float tcB = 1.f - 2.f * __builtin_amdgcn_rcpf(
                  1.f + __builtin_amdgcn_exp2f((2.0f * LOG2E) * cB));
    float hvA = ogA * tcA;
    float hvB = ogB * tcB;
    hwA[woff] = (uint16_t)cvtpk(hvA, hvA);
    hwB[woff] = (uint16_t)cvtpk(hvB, hvB);
  };

  for (int t = 0; t < T - 2; t += 2) {
    step(xa0A, xb0A, xa0B, xb0B, true, hbuf[0][0], hbuf[0][1], hbuf[1][0], hbuf[1][1]);
    step(xa1A, xb1A, xa1B, xb1B, true, hbuf[1][0], hbuf[1][1], hbuf[0][0], hbuf[0][1]);
  }
  step(xa0A, xb0A, xa0B, xb0B, false, hbuf[0][0], hbuf[0][1], hbuf[1][0], hbuf[1][1]);
  step(xa1A, xb1A, xa1B, xb1B, false, hbuf[1][0], hbuf[1][1], hbuf[0][0], hbuf[0][1]);

  __syncthreads();  // final h (bf16) in hbuf[0][chain], linear [row][col]

  // ---- epilogue: logits = h_last @ fc_W^T + fc_b (8 rows x 10 cols) ----
  if (tid < 80) {
    const int m = tid / 10, cl = tid % 10;   // m: 0..7 -> chain m>>2, row m&3
    float s = fc_b[cl];
    const float* wr = fc_W + cl * HH;
    const uint16_t* hm = hbuf[0][m >> 2] + (m & 3) * HSTRIDE;
    #pragma unroll
    for (int k = 0; k < HH; ++k) {
      union { uint32_t u; float f; } v;
      v.u = (uint32_t)hm[k] << 16;
      s += v.f * wr[k];
    }
    out[(size_t)(bm + m) * 10 + cl] = s;
  }
}

extern "C" void kernel_launch(void* const* d_in, const int* in_sizes, int n_in,
                              void* d_out, int out_size, void* d_ws, size_t ws_size,
                              hipStream_t stream) {
  const float* x    = (const float*)d_in[0];
  const float* W_ih = (const float*)d_in[1];
  const float* W_hh = (const float*)d_in[2];
  const float* b_ih = (const float*)d_in[3];
  const float* b_hh = (const float*)d_in[4];
  const float* fc_W = (const float*)d_in[5];
  const float* fc_b = (const float*)d_in[6];
  float* out = (float*)d_out;

  const int B = out_size / 10;            // 2048
  const int T = in_sizes[0] / (B * DD);   // 1024

  dim3 grid(B / 8), block(256);
  hipLaunchKernelGGL(lstm_fused, grid, block, 0, stream,
                     x, W_ih, W_hh, b_ih, b_hh, fc_W, fc_b, out, T);
}